// Round 6
// baseline (302.426 us; speedup 1.0000x reference)
//
#include <hip/hip_runtime.h>
#include <hip/hip_bf16.h>

typedef __attribute__((ext_vector_type(8))) __bf16 bf16x8;
typedef __attribute__((ext_vector_type(4))) __bf16 bf16x4;
typedef __attribute__((ext_vector_type(4))) float f32x4;
typedef __attribute__((ext_vector_type(2))) float f32x2;

#define MFMA(a, b, c) __builtin_amdgcn_mfma_f32_16x16x32_bf16((a), (b), (c), 0, 0, 0)

__device__ __forceinline__ bf16x8 pack8(f32x4 a, f32x4 b) {
    bf16x8 r;
    r[0] = (__bf16)a[0]; r[1] = (__bf16)a[1]; r[2] = (__bf16)a[2]; r[3] = (__bf16)a[3];
    r[4] = (__bf16)b[0]; r[5] = (__bf16)b[1]; r[6] = (__bf16)b[2]; r[7] = (__bf16)b[3];
    return r;
}

__device__ __forceinline__ bf16x8 cvt8(const float* __restrict__ p) {
    return pack8(*(const f32x4*)(p), *(const f32x4*)(p + 4));
}

// ---------------------------------------------------------------------------
// Kernel 1 (transposed): y1 = x @ W1a[0:128,:] + b1a ; y2 = x @ W2a[0:128,:] + b2a
// ---------------------------------------------------------------------------
__global__ __launch_bounds__(256) void precompute_y(
    const float* __restrict__ x,
    const float* __restrict__ W1a, const float* __restrict__ b1a,
    const float* __restrict__ W2a, const float* __restrict__ b2a,
    float* __restrict__ y1, float* __restrict__ y2,
    int N, int ntiles)
{
    const int LDK = 136;                       // 128 + 8 pad
    __shared__ __align__(16) __bf16 w1t[64 * 136];
    __shared__ __align__(16) __bf16 w2t[64 * 136];
    for (int idx = threadIdx.x; idx < 64 * 128; idx += 256) {
        int k = idx >> 6, n = idx & 63;
        w1t[n * LDK + k] = (__bf16)W1a[k * 64 + n];
        w2t[n * LDK + k] = (__bf16)W2a[k * 64 + n];
    }
    __syncthreads();

    const int lane = threadIdx.x & 63, wave = threadIdx.x >> 6;
    const int l15 = lane & 15, l4 = lane >> 4;

    f32x4 bias1[4], bias2[4];
#pragma unroll
    for (int nt = 0; nt < 4; ++nt) {
        bias1[nt] = *(const f32x4*)(b1a + nt * 16 + l4 * 4);
        bias2[nt] = *(const f32x4*)(b2a + nt * 16 + l4 * 4);
    }

    for (int tile = blockIdx.x * 4 + wave; tile < ntiles; tile += gridDim.x * 4) {
        const int node = tile * 16 + l15;
        const int nrow = min(node, N - 1);
        f32x4 acc1[4], acc2[4];
#pragma unroll
        for (int nt = 0; nt < 4; ++nt) {
            acc1[nt] = (f32x4){0.f, 0.f, 0.f, 0.f};
            acc2[nt] = (f32x4){0.f, 0.f, 0.f, 0.f};
        }
#pragma unroll
        for (int j = 0; j < 4; ++j) {
            const int k0 = j * 32 + l4 * 8;
            bf16x8 b = cvt8(x + (size_t)nrow * 128 + k0);     // B = x^T (lane l15 = node)
#pragma unroll
            for (int nt = 0; nt < 4; ++nt) {
                bf16x8 a1 = *(const bf16x8*)(w1t + (nt * 16 + l15) * LDK + k0);  // A = W^T rows
                acc1[nt] = MFMA(a1, b, acc1[nt]);
                bf16x8 a2 = *(const bf16x8*)(w2t + (nt * 16 + l15) * LDK + k0);
                acc2[nt] = MFMA(a2, b, acc2[nt]);
            }
        }
        if (node < N) {
#pragma unroll
            for (int nt = 0; nt < 4; ++nt) {
                f32x4 v1 = acc1[nt] + bias1[nt];
                f32x4 v2 = acc2[nt] + bias2[nt];
                *(f32x4*)(y1 + (size_t)node * 64 + nt * 16 + l4 * 4) = v1;
                *(f32x4*)(y2 + (size_t)node * 64 + nt * 16 + l4 * 4) = v2;
            }
        }
    }
}

// ---------------------------------------------------------------------------
// CSR build: histogram -> single-block scan -> scatter
// ---------------------------------------------------------------------------
__global__ __launch_bounds__(256) void hist_kernel(
    const int* __restrict__ recv, int* __restrict__ cnt, int E)
{
    for (int e = blockIdx.x * blockDim.x + threadIdx.x; e < E;
         e += gridDim.x * blockDim.x)
        atomicAdd(&cnt[recv[e]], 1);
}

__global__ __launch_bounds__(1024) void scan_offsets(
    const int* __restrict__ cnt, int* __restrict__ offs, int* __restrict__ cur, int N)
{
    __shared__ int wsum[16];
    __shared__ int stot;
    const int tid = threadIdx.x;
    const int lane = tid & 63, wave = tid >> 6;
    int carry = 0;
    const int CH = 4096;                       // 1024 threads x 4 elems
    for (int base = 0; base < N; base += CH) {
        const int idx = base + tid * 4;
        int v0 = (idx + 0 < N) ? cnt[idx + 0] : 0;
        int v1 = (idx + 1 < N) ? cnt[idx + 1] : 0;
        int v2 = (idx + 2 < N) ? cnt[idx + 2] : 0;
        int v3 = (idx + 3 < N) ? cnt[idx + 3] : 0;
        const int t = v0 + v1 + v2 + v3;
        int s = t;                              // inclusive wave scan
#pragma unroll
        for (int d = 1; d < 64; d <<= 1) {
            int u = __shfl_up(s, d);
            if (lane >= d) s += u;
        }
        if (lane == 63) wsum[wave] = s;
        __syncthreads();
        if (wave == 0) {
            int w = (lane < 16) ? wsum[lane] : 0;
            int ws = w;
#pragma unroll
            for (int d = 1; d < 16; d <<= 1) {
                int u = __shfl_up(ws, d);
                if (lane >= d) ws += u;
            }
            if (lane < 16) wsum[lane] = ws - w;  // exclusive wave offsets
            if (lane == 15) stot = ws;
        }
        __syncthreads();
        const int excl = s - t + wsum[wave] + carry;
        if (idx + 0 < N) { offs[idx+0] = excl;                cur[idx+0] = excl; }
        if (idx + 1 < N) { offs[idx+1] = excl+v0;             cur[idx+1] = excl+v0; }
        if (idx + 2 < N) { offs[idx+2] = excl+v0+v1;          cur[idx+2] = excl+v0+v1; }
        if (idx + 3 < N) { offs[idx+3] = excl+v0+v1+v2;       cur[idx+3] = excl+v0+v1+v2; }
        carry += stot;
        __syncthreads();                        // protect wsum/stot for next chunk
    }
    if (tid == 0) offs[N] = carry;
}

__global__ __launch_bounds__(256) void scatter_kernel(
    const int* __restrict__ recv, int* __restrict__ cur, int* __restrict__ elist, int E)
{
    for (int e = blockIdx.x * blockDim.x + threadIdx.x; e < E;
         e += gridDim.x * blockDim.x) {
        const int p = atomicAdd(&cur[recv[e]], 1);
        elist[p] = e;
    }
}

// ---------------------------------------------------------------------------
// Kernel 2: per-edge  pre1 = y1[send] + eattr @ W1a[128:192,:]
//   msg = relu( relu(pre1) @ W1b + b1b )
// MODE 0: store msg[e] as bf16 (CSR path).   MODE 1: unsafeAtomicAdd into agg.
// Edges processed in natural order -> eattr stream fully coalesced.
// ---------------------------------------------------------------------------
template<int MODE>
__global__ __launch_bounds__(256) void edge_mlp(
    const float* __restrict__ eattr,
    const int* __restrict__ send, const int* __restrict__ recv,
    const float* __restrict__ W1a, const float* __restrict__ W1b,
    const float* __restrict__ b1b,
    const float* __restrict__ y1,
    __bf16* __restrict__ msg, float* agg,
    int E, int ntiles)
{
    const int LDK = 72;                        // 64 + 8 pad
    __shared__ __align__(16) __bf16 wat[64 * 72];   // W1a[128:192,:]^T
    __shared__ __align__(16) __bf16 wbt[64 * 72];   // W1b^T
    __shared__ __align__(16) __bf16 hbuf[4][16 * 72];
    for (int idx = threadIdx.x; idx < 64 * 64; idx += 256) {
        int k = idx >> 6, n = idx & 63;
        wat[n * LDK + k] = (__bf16)W1a[(128 + k) * 64 + n];
        wbt[n * LDK + k] = (__bf16)W1b[k * 64 + n];
    }
    __syncthreads();

    const int lane = threadIdx.x & 63, wave = threadIdx.x >> 6;
    const int l15 = lane & 15, l4 = lane >> 4;
    __bf16* hb = hbuf[wave];

    f32x4 biasb[4];
#pragma unroll
    for (int nt = 0; nt < 4; ++nt) biasb[nt] = *(const f32x4*)(b1b + nt * 16 + l4 * 4);

    for (int tile = blockIdx.x * 4 + wave; tile < ntiles; tile += gridDim.x * 4) {
        const int e = tile * 16 + l15;
        const int eload = min(e, E - 1);
        const int s = send[eload];

        // ---- layer 1 (transposed): C-init = y1[send] vectorized gather
        f32x4 acc[4];
#pragma unroll
        for (int nt = 0; nt < 4; ++nt)
            acc[nt] = *(const f32x4*)(y1 + (size_t)s * 64 + nt * 16 + l4 * 4);
#pragma unroll
        for (int j = 0; j < 2; ++j) {
            const int k0 = j * 32 + l4 * 8;
            bf16x8 b = cvt8(eattr + (size_t)eload * 64 + k0);
#pragma unroll
            for (int nt = 0; nt < 4; ++nt) {
                bf16x8 a = *(const bf16x8*)(wat + (nt * 16 + l15) * LDK + k0);
                acc[nt] = MFMA(a, b, acc[nt]);
            }
        }
        // relu -> stage h tile (edge = l15 row)
#pragma unroll
        for (int nt = 0; nt < 4; ++nt) {
            bf16x4 hv;
#pragma unroll
            for (int r = 0; r < 4; ++r) hv[r] = (__bf16)fmaxf(acc[nt][r], 0.f);
            *(bf16x4*)(hb + l15 * LDK + nt * 16 + l4 * 4) = hv;
        }

        // ---- layer 2 (transposed): lane l15 = edge, cols nt*16 + l4*4 + r
        f32x4 acc2[4];
#pragma unroll
        for (int nt = 0; nt < 4; ++nt) acc2[nt] = biasb[nt];
#pragma unroll
        for (int j = 0; j < 2; ++j) {
            const int k0 = j * 32 + l4 * 8;
            bf16x8 b = *(const bf16x8*)(hb + l15 * LDK + k0);
#pragma unroll
            for (int nt = 0; nt < 4; ++nt) {
                bf16x8 a = *(const bf16x8*)(wbt + (nt * 16 + l15) * LDK + k0);
                acc2[nt] = MFMA(a, b, acc2[nt]);
            }
        }

        if (e < E) {
            if (MODE == 0) {
#pragma unroll
                for (int nt = 0; nt < 4; ++nt) {
                    bf16x4 mv;
#pragma unroll
                    for (int r = 0; r < 4; ++r) mv[r] = (__bf16)fmaxf(acc2[nt][r], 0.f);
                    *(bf16x4*)(msg + (size_t)e * 64 + nt * 16 + l4 * 4) = mv;
                }
            } else {
                const int rv = recv[eload];
                float* base = agg + (size_t)rv * 64 + l4 * 4;
#pragma unroll
                for (int nt = 0; nt < 4; ++nt)
#pragma unroll
                    for (int r = 0; r < 4; ++r)
                        unsafeAtomicAdd(base + nt * 16 + r, fmaxf(acc2[nt][r], 0.f));
            }
        }
    }
}

// ---------------------------------------------------------------------------
// CSR reduce: one WAVE per node; lanes 0-31 / 32-63 take alternate edges.
// Lane accumulates 2 columns in f32; shfl_xor(32) combines halves.
// ---------------------------------------------------------------------------
__global__ __launch_bounds__(256) void csr_reduce(
    const unsigned* __restrict__ msg_u,
    const int* __restrict__ offs, const int* __restrict__ elist,
    float* __restrict__ agg, int N)
{
    const int wave = threadIdx.x >> 6, lane = threadIdx.x & 63;
    const int half = lane >> 5, c = lane & 31;
    for (int node = blockIdx.x * 4 + wave; node < N; node += gridDim.x * 4) {
        const int oL = offs[node], oR = offs[node + 1];
        float ax = 0.f, ay = 0.f;
        for (int p = oL + half; p < oR; p += 2) {
            const int e = elist[p];
            const unsigned u = msg_u[(size_t)e * 32 + c];
            ax += __uint_as_float(u << 16);
            ay += __uint_as_float(u & 0xffff0000u);
        }
        ax += __shfl_xor(ax, 32);
        ay += __shfl_xor(ay, 32);
        if (half == 0) {
            f32x2 v = {ax, ay};
            *(f32x2*)(agg + (size_t)node * 64 + c * 2) = v;
        }
    }
}

// ---------------------------------------------------------------------------
// Kernel 3 (transposed): per-node  pre = y2[n] + agg[n] @ W2a[128:192,:]
//   out = relu( relu(pre) @ W2b + b2b )
// ---------------------------------------------------------------------------
__global__ __launch_bounds__(256) void node_pass(
    const float* __restrict__ agg,
    const float* __restrict__ W2a, const float* __restrict__ W2b,
    const float* __restrict__ b2b,
    const float* __restrict__ y2, float* __restrict__ out,
    int N, int ntiles)
{
    const int LDK = 72;
    __shared__ __align__(16) __bf16 wat[64 * 72];   // W2a[128:192,:]^T
    __shared__ __align__(16) __bf16 wbt[64 * 72];   // W2b^T
    __shared__ __align__(16) __bf16 hbuf[4][16 * 72];
    for (int idx = threadIdx.x; idx < 64 * 64; idx += 256) {
        int k = idx >> 6, n = idx & 63;
        wat[n * LDK + k] = (__bf16)W2a[(128 + k) * 64 + n];
        wbt[n * LDK + k] = (__bf16)W2b[k * 64 + n];
    }
    __syncthreads();

    const int lane = threadIdx.x & 63, wave = threadIdx.x >> 6;
    const int l15 = lane & 15, l4 = lane >> 4;
    __bf16* hb = hbuf[wave];

    f32x4 biasb[4];
#pragma unroll
    for (int nt = 0; nt < 4; ++nt) biasb[nt] = *(const f32x4*)(b2b + nt * 16 + l4 * 4);

    for (int tile = blockIdx.x * 4 + wave; tile < ntiles; tile += gridDim.x * 4) {
        const int node = tile * 16 + l15;
        const int nrow = min(node, N - 1);

        f32x4 acc[4];
#pragma unroll
        for (int nt = 0; nt < 4; ++nt)
            acc[nt] = *(const f32x4*)(y2 + (size_t)nrow * 64 + nt * 16 + l4 * 4);
#pragma unroll
        for (int j = 0; j < 2; ++j) {
            const int k0 = j * 32 + l4 * 8;
            bf16x8 b = cvt8(agg + (size_t)nrow * 64 + k0);
#pragma unroll
            for (int nt = 0; nt < 4; ++nt) {
                bf16x8 a = *(const bf16x8*)(wat + (nt * 16 + l15) * LDK + k0);
                acc[nt] = MFMA(a, b, acc[nt]);
            }
        }
#pragma unroll
        for (int nt = 0; nt < 4; ++nt) {
            bf16x4 hv;
#pragma unroll
            for (int r = 0; r < 4; ++r) hv[r] = (__bf16)fmaxf(acc[nt][r], 0.f);
            *(bf16x4*)(hb + l15 * LDK + nt * 16 + l4 * 4) = hv;
        }

        f32x4 acc2[4];
#pragma unroll
        for (int nt = 0; nt < 4; ++nt) acc2[nt] = biasb[nt];
#pragma unroll
        for (int j = 0; j < 2; ++j) {
            const int k0 = j * 32 + l4 * 8;
            bf16x8 b = *(const bf16x8*)(hb + l15 * LDK + k0);
#pragma unroll
            for (int nt = 0; nt < 4; ++nt) {
                bf16x8 a = *(const bf16x8*)(wbt + (nt * 16 + l15) * LDK + k0);
                acc2[nt] = MFMA(a, b, acc2[nt]);
            }
        }
        if (node < N) {
#pragma unroll
            for (int nt = 0; nt < 4; ++nt) {
                f32x4 v;
#pragma unroll
                for (int r = 0; r < 4; ++r) v[r] = fmaxf(acc2[nt][r], 0.f);
                *(f32x4*)(out + (size_t)node * 64 + nt * 16 + l4 * 4) = v;
            }
        }
    }
}

// ---------------------------------------------------------------------------
extern "C" void kernel_launch(void* const* d_in, const int* in_sizes, int n_in,
                              void* d_out, int out_size, void* d_ws, size_t ws_size,
                              hipStream_t stream) {
    const float* x     = (const float*)d_in[0];
    const int*   eidx  = (const int*)d_in[1];
    const float* eattr = (const float*)d_in[2];
    // d_in[3] = u (unused), d_in[4] = batch (unused)
    const float* W1a = (const float*)d_in[5];
    const float* b1a = (const float*)d_in[6];
    const float* W1b = (const float*)d_in[7];
    const float* b1b = (const float*)d_in[8];
    const float* W2a = (const float*)d_in[9];
    const float* b2a = (const float*)d_in[10];
    const float* W2b = (const float*)d_in[11];
    const float* b2b = (const float*)d_in[12];
    float* out = (float*)d_out;

    const int N = in_sizes[0] / 128;
    const int E = in_sizes[1] / 2;
    const int* send = eidx;
    const int* recv = eidx + E;

    const size_t NG = (size_t)N * 64;
    const size_t need = 2 * NG * sizeof(float) + (size_t)E * 64 * sizeof(__bf16)
                      + ((size_t)3 * (N + 1) + E) * sizeof(int);
    const bool big = ws_size >= need;

    const int ntilesN = (N + 15) / 16;
    const int ntilesE = (E + 15) / 16;
    int blkN = (ntilesN + 3) / 4;
    if (blkN > 1024) blkN = 1024;
    int blkE = (ntilesE + 3) / 4;
    if (blkE > 1280) blkE = 1280;
    int blkS = (E + 255) / 256;
    if (blkS > 2048) blkS = 2048;
    int blkR = (N + 3) / 4;
    if (blkR > 2048) blkR = 2048;

    if (big) {
        // layout: y1 | y2 | msg(bf16) | cnt | offs | cur | elist ; agg reuses y1
        float*  y1    = (float*)d_ws;
        float*  y2    = y1 + NG;
        __bf16* msg   = (__bf16*)(y2 + NG);
        int*    cnt   = (int*)(msg + (size_t)E * 64);
        int*    offs  = cnt + (N + 1);
        int*    cur   = offs + (N + 1);
        int*    elist = cur + (N + 1);
        float*  agg   = y1;                     // reused after edge_mlp

        hipMemsetAsync(cnt, 0, (size_t)(N + 1) * sizeof(int), stream);
        precompute_y<<<blkN, 256, 0, stream>>>(x, W1a, b1a, W2a, b2a, y1, y2, N, ntilesN);
        edge_mlp<0><<<blkE, 256, 0, stream>>>(eattr, send, recv, W1a, W1b, b1b,
                                              y1, msg, nullptr, E, ntilesE);
        hist_kernel<<<blkS, 256, 0, stream>>>(recv, cnt, E);
        scan_offsets<<<1, 1024, 0, stream>>>(cnt, offs, cur, N);
        scatter_kernel<<<blkS, 256, 0, stream>>>(recv, cur, elist, E);
        csr_reduce<<<blkR, 256, 0, stream>>>((const unsigned*)msg, offs, elist, agg, N);
        node_pass<<<blkN, 256, 0, stream>>>(agg, W2a, W2b, b2b, y2, out, N, ntilesN);
    } else {
        // fallback: agg | y1 | y2 with device-atomic scatter
        float* agg = (float*)d_ws;
        float* y1  = agg + NG;
        float* y2  = y1 + NG;
        hipMemsetAsync(agg, 0, NG * sizeof(float), stream);
        precompute_y<<<blkN, 256, 0, stream>>>(x, W1a, b1a, W2a, b2a, y1, y2, N, ntilesN);
        edge_mlp<1><<<blkE, 256, 0, stream>>>(eattr, send, recv, W1a, W1b, b1b,
                                              y1, nullptr, agg, E, ntilesE);
        node_pass<<<blkN, 256, 0, stream>>>(agg, W2a, W2b, b2b, y2, out, N, ntilesN);
    }
}

// Round 7
// 249.435 us; speedup vs baseline: 1.2124x; 1.2124x over previous
//
#include <hip/hip_runtime.h>
#include <hip/hip_bf16.h>

typedef __attribute__((ext_vector_type(8))) __bf16 bf16x8;
typedef __attribute__((ext_vector_type(4))) __bf16 bf16x4;
typedef __attribute__((ext_vector_type(2))) __bf16 bf16x2;
typedef __attribute__((ext_vector_type(4))) float f32x4;

#define MFMA(a, b, c) __builtin_amdgcn_mfma_f32_16x16x32_bf16((a), (b), (c), 0, 0, 0)

__device__ __forceinline__ bf16x8 pack8(f32x4 a, f32x4 b) {
    bf16x8 r;
    r[0] = (__bf16)a[0]; r[1] = (__bf16)a[1]; r[2] = (__bf16)a[2]; r[3] = (__bf16)a[3];
    r[4] = (__bf16)b[0]; r[5] = (__bf16)b[1]; r[6] = (__bf16)b[2]; r[7] = (__bf16)b[3];
    return r;
}

__device__ __forceinline__ bf16x8 cvt8(const float* __restrict__ p) {
    return pack8(*(const f32x4*)(p), *(const f32x4*)(p + 4));
}

// ---------------------------------------------------------------------------
// tiny zero kernel (replaces hipMemsetAsync: graph-captured fillBufferAligned
// cost 119 us/replay in round 6)
// ---------------------------------------------------------------------------
__global__ __launch_bounds__(256) void zero_i32(int* __restrict__ p, int n) {
    for (int i = blockIdx.x * blockDim.x + threadIdx.x; i < n;
         i += gridDim.x * blockDim.x)
        p[i] = 0;
}

// ---------------------------------------------------------------------------
// Kernel 1 (transposed): y1 = x @ W1a[0:128,:] + b1a ; y2 = x @ W2a[0:128,:] + b2a
// ---------------------------------------------------------------------------
__global__ __launch_bounds__(256) void precompute_y(
    const float* __restrict__ x,
    const float* __restrict__ W1a, const float* __restrict__ b1a,
    const float* __restrict__ W2a, const float* __restrict__ b2a,
    float* __restrict__ y1, float* __restrict__ y2,
    int N, int ntiles)
{
    const int LDK = 136;                       // 128 + 8 pad
    __shared__ __align__(16) __bf16 w1t[64 * 136];
    __shared__ __align__(16) __bf16 w2t[64 * 136];
    for (int idx = threadIdx.x; idx < 64 * 128; idx += 256) {
        int k = idx >> 6, n = idx & 63;
        w1t[n * LDK + k] = (__bf16)W1a[k * 64 + n];
        w2t[n * LDK + k] = (__bf16)W2a[k * 64 + n];
    }
    __syncthreads();

    const int lane = threadIdx.x & 63, wave = threadIdx.x >> 6;
    const int l15 = lane & 15, l4 = lane >> 4;

    f32x4 bias1[4], bias2[4];
#pragma unroll
    for (int nt = 0; nt < 4; ++nt) {
        bias1[nt] = *(const f32x4*)(b1a + nt * 16 + l4 * 4);
        bias2[nt] = *(const f32x4*)(b2a + nt * 16 + l4 * 4);
    }

    for (int tile = blockIdx.x * 4 + wave; tile < ntiles; tile += gridDim.x * 4) {
        const int node = tile * 16 + l15;
        const int nrow = min(node, N - 1);
        f32x4 acc1[4], acc2[4];
#pragma unroll
        for (int nt = 0; nt < 4; ++nt) {
            acc1[nt] = (f32x4){0.f, 0.f, 0.f, 0.f};
            acc2[nt] = (f32x4){0.f, 0.f, 0.f, 0.f};
        }
#pragma unroll
        for (int j = 0; j < 4; ++j) {
            const int k0 = j * 32 + l4 * 8;
            bf16x8 b = cvt8(x + (size_t)nrow * 128 + k0);     // B = x^T (lane l15 = node)
#pragma unroll
            for (int nt = 0; nt < 4; ++nt) {
                bf16x8 a1 = *(const bf16x8*)(w1t + (nt * 16 + l15) * LDK + k0);  // A = W^T rows
                acc1[nt] = MFMA(a1, b, acc1[nt]);
                bf16x8 a2 = *(const bf16x8*)(w2t + (nt * 16 + l15) * LDK + k0);
                acc2[nt] = MFMA(a2, b, acc2[nt]);
            }
        }
        if (node < N) {
#pragma unroll
            for (int nt = 0; nt < 4; ++nt) {
                f32x4 v1 = acc1[nt] + bias1[nt];
                f32x4 v2 = acc2[nt] + bias2[nt];
                *(f32x4*)(y1 + (size_t)node * 64 + nt * 16 + l4 * 4) = v1;
                *(f32x4*)(y2 + (size_t)node * 64 + nt * 16 + l4 * 4) = v2;
            }
        }
    }
}

// ---------------------------------------------------------------------------
// CSR build: histogram -> single-block scan (offs and running cursor cur)
// ---------------------------------------------------------------------------
__global__ __launch_bounds__(256) void hist_kernel(
    const int* __restrict__ recv, int* __restrict__ cnt, int E)
{
    for (int e = blockIdx.x * blockDim.x + threadIdx.x; e < E;
         e += gridDim.x * blockDim.x)
        atomicAdd(&cnt[recv[e]], 1);
}

__global__ __launch_bounds__(1024) void scan_offsets(
    const int* __restrict__ cnt, int* __restrict__ offs, int* __restrict__ cur, int N)
{
    __shared__ int wsum[16];
    __shared__ int stot;
    const int tid = threadIdx.x;
    const int lane = tid & 63, wave = tid >> 6;
    int carry = 0;
    const int CH = 4096;                       // 1024 threads x 4 elems
    for (int base = 0; base < N; base += CH) {
        const int idx = base + tid * 4;
        int v0 = (idx + 0 < N) ? cnt[idx + 0] : 0;
        int v1 = (idx + 1 < N) ? cnt[idx + 1] : 0;
        int v2 = (idx + 2 < N) ? cnt[idx + 2] : 0;
        int v3 = (idx + 3 < N) ? cnt[idx + 3] : 0;
        const int t = v0 + v1 + v2 + v3;
        int s = t;                              // inclusive wave scan
#pragma unroll
        for (int d = 1; d < 64; d <<= 1) {
            int u = __shfl_up(s, d);
            if (lane >= d) s += u;
        }
        if (lane == 63) wsum[wave] = s;
        __syncthreads();
        if (wave == 0) {
            int w = (lane < 16) ? wsum[lane] : 0;
            int ws = w;
#pragma unroll
            for (int d = 1; d < 16; d <<= 1) {
                int u = __shfl_up(ws, d);
                if (lane >= d) ws += u;
            }
            if (lane < 16) wsum[lane] = ws - w;  // exclusive wave offsets
            if (lane == 15) stot = ws;
        }
        __syncthreads();
        const int excl = s - t + wsum[wave] + carry;
        if (idx + 0 < N) { offs[idx+0] = excl;                cur[idx+0] = excl; }
        if (idx + 1 < N) { offs[idx+1] = excl+v0;             cur[idx+1] = excl+v0; }
        if (idx + 2 < N) { offs[idx+2] = excl+v0+v1;          cur[idx+2] = excl+v0+v1; }
        if (idx + 3 < N) { offs[idx+3] = excl+v0+v1+v2;       cur[idx+3] = excl+v0+v1+v2; }
        carry += stot;
        __syncthreads();                        // protect wsum/stot for next chunk
    }
    if (tid == 0) offs[N] = carry;
}

// ---------------------------------------------------------------------------
// Kernel 2: per-edge MLP, software-pipelined 1 tile deep.
//   pre1 = y1[send] + eattr @ W1a[128:192,:]; msg = relu(relu(pre1) @ W1b + b1b)
// MODE 0: p = atomicAdd(cur[recv]) once per edge; write msg row at CSR slot p
//         (bf16) -> csr_reduce later streams rows contiguously. No elist.
// MODE 1: fallback, device fp atomics into agg.
// ---------------------------------------------------------------------------
template<int MODE>
__global__ __launch_bounds__(256) void edge_mlp(
    const float* __restrict__ eattr,
    const int* __restrict__ send, const int* __restrict__ recv,
    const float* __restrict__ W1a, const float* __restrict__ W1b,
    const float* __restrict__ b1b,
    const float* __restrict__ y1,
    int* __restrict__ cur, __bf16* __restrict__ msgC, float* agg,
    int E, int ntiles)
{
    const int LDK = 72;                        // 64 + 8 pad
    __shared__ __align__(16) __bf16 wat[64 * 72];   // W1a[128:192,:]^T
    __shared__ __align__(16) __bf16 wbt[64 * 72];   // W1b^T
    __shared__ __align__(16) __bf16 hbuf[4][16 * 72];
    for (int idx = threadIdx.x; idx < 64 * 64; idx += 256) {
        int k = idx >> 6, n = idx & 63;
        wat[n * LDK + k] = (__bf16)W1a[(128 + k) * 64 + n];
        wbt[n * LDK + k] = (__bf16)W1b[k * 64 + n];
    }
    __syncthreads();

    const int lane = threadIdx.x & 63, wave = threadIdx.x >> 6;
    const int l15 = lane & 15, l4 = lane >> 4;
    __bf16* hb = hbuf[wave];

    f32x4 biasb[4];
#pragma unroll
    for (int nt = 0; nt < 4; ++nt) biasb[nt] = *(const f32x4*)(b1b + nt * 16 + l4 * 4);

    int tile = blockIdx.x * 4 + wave;
    const int stride = gridDim.x * 4;
    if (tile >= ntiles) return;

    // ---- prologue: loads for the first tile
    int e  = tile * 16 + l15;
    int el = min(e, E - 1);
    int s  = send[el];
    int rv = recv[el];
    f32x4 ea[4], cin[4];
    {
        const float* ep = eattr + (size_t)el * 64 + l4 * 8;
        ea[0] = *(const f32x4*)(ep);      ea[1] = *(const f32x4*)(ep + 4);
        ea[2] = *(const f32x4*)(ep + 32); ea[3] = *(const f32x4*)(ep + 36);
#pragma unroll
        for (int nt = 0; nt < 4; ++nt)
            cin[nt] = *(const f32x4*)(y1 + (size_t)s * 64 + nt * 16 + l4 * 4);
    }

    while (true) {
        const int tnext = tile + stride;
        const bool have_next = tnext < ntiles;
        int e_n = e, el_n = el, s_n = s, rv_n = rv;
        if (have_next) {                       // issue next-tile index loads early
            e_n  = tnext * 16 + l15;
            el_n = min(e_n, E - 1);
            s_n  = send[el_n];
            rv_n = recv[el_n];
        }
        // CSR slot for current edge (one atomic per edge, lanes l4==0)
        int p = 0;
        if (MODE == 0 && l4 == 0 && e < E) p = atomicAdd(&cur[rv], 1);

        // ---- layer 1 (transposed): C-init = y1[send] (prefetched last iter)
        f32x4 acc[4] = {cin[0], cin[1], cin[2], cin[3]};
#pragma unroll
        for (int j = 0; j < 2; ++j) {
            bf16x8 b = pack8(ea[2 * j], ea[2 * j + 1]);
            const int k0 = j * 32 + l4 * 8;
#pragma unroll
            for (int nt = 0; nt < 4; ++nt) {
                bf16x8 a = *(const bf16x8*)(wat + (nt * 16 + l15) * LDK + k0);
                acc[nt] = MFMA(a, b, acc[nt]);
            }
        }
        // ---- prefetch next tile's eattr + y1 gather (hidden under layer 2)
        f32x4 ea_n[4], cin_n[4];
        if (have_next) {
            const float* ep = eattr + (size_t)el_n * 64 + l4 * 8;
            ea_n[0] = *(const f32x4*)(ep);      ea_n[1] = *(const f32x4*)(ep + 4);
            ea_n[2] = *(const f32x4*)(ep + 32); ea_n[3] = *(const f32x4*)(ep + 36);
#pragma unroll
            for (int nt = 0; nt < 4; ++nt)
                cin_n[nt] = *(const f32x4*)(y1 + (size_t)s_n * 64 + nt * 16 + l4 * 4);
        }
        // relu -> stage h tile (edge = l15 row)
#pragma unroll
        for (int nt = 0; nt < 4; ++nt) {
            bf16x4 hv;
#pragma unroll
            for (int r = 0; r < 4; ++r) hv[r] = (__bf16)fmaxf(acc[nt][r], 0.f);
            *(bf16x4*)(hb + l15 * LDK + nt * 16 + l4 * 4) = hv;
        }
        // ---- layer 2 (transposed): lane l15 = edge, cols nt*16 + l4*4 + r
        f32x4 acc2[4];
#pragma unroll
        for (int nt = 0; nt < 4; ++nt) acc2[nt] = biasb[nt];
#pragma unroll
        for (int j = 0; j < 2; ++j) {
            const int k0 = j * 32 + l4 * 8;
            bf16x8 b = *(const bf16x8*)(hb + l15 * LDK + k0);
#pragma unroll
            for (int nt = 0; nt < 4; ++nt) {
                bf16x8 a = *(const bf16x8*)(wbt + (nt * 16 + l15) * LDK + k0);
                acc2[nt] = MFMA(a, b, acc2[nt]);
            }
        }
        // ---- emit
        if (MODE == 0) {
            const int pb = __shfl(p, l15);     // broadcast edge's CSR slot
            if (e < E) {
                __bf16* row = msgC + (size_t)pb * 64;
#pragma unroll
                for (int nt = 0; nt < 4; ++nt) {
                    bf16x4 mv;
#pragma unroll
                    for (int r = 0; r < 4; ++r) mv[r] = (__bf16)fmaxf(acc2[nt][r], 0.f);
                    *(bf16x4*)(row + nt * 16 + l4 * 4) = mv;
                }
            }
        } else {
            if (e < E) {
                float* base = agg + (size_t)rv * 64 + l4 * 4;
#pragma unroll
                for (int nt = 0; nt < 4; ++nt)
#pragma unroll
                    for (int r = 0; r < 4; ++r)
                        unsafeAtomicAdd(base + nt * 16 + r, fmaxf(acc2[nt][r], 0.f));
            }
        }
        if (!have_next) break;
        tile = tnext; e = e_n; el = el_n; s = s_n; rv = rv_n;
#pragma unroll
        for (int i = 0; i < 4; ++i) { ea[i] = ea_n[i]; cin[i] = cin_n[i]; }
    }
}

// ---------------------------------------------------------------------------
// CSR reduce (streaming): msg rows for node n are CONTIGUOUS [offs[n],offs[n+1]).
// One wave per node; halves take alternate rows; lane sums 2 columns in f32.
// Output agg as bf16 (it is only ever consumed as an MFMA B operand).
// ---------------------------------------------------------------------------
__global__ __launch_bounds__(256) void csr_reduce(
    const unsigned* __restrict__ msg_u,
    const int* __restrict__ offs,
    __bf16* __restrict__ aggB, int N)
{
    const int wave = threadIdx.x >> 6, lane = threadIdx.x & 63;
    const int half = lane >> 5, c = lane & 31;
    for (int node = blockIdx.x * 4 + wave; node < N; node += gridDim.x * 4) {
        const int oL = offs[node], oR = offs[node + 1];
        float ax = 0.f, ay = 0.f;
        for (int p = oL + half; p < oR; p += 2) {
            const unsigned u = msg_u[(size_t)p * 32 + c];
            ax += __uint_as_float(u << 16);
            ay += __uint_as_float(u & 0xffff0000u);
        }
        ax += __shfl_xor(ax, 32);
        ay += __shfl_xor(ay, 32);
        if (half == 0) {
            bf16x2 v; v[0] = (__bf16)ax; v[1] = (__bf16)ay;
            *(bf16x2*)(aggB + (size_t)node * 64 + c * 2) = v;
        }
    }
}

// ---------------------------------------------------------------------------
// Kernel 3 (transposed): per-node  pre = y2[n] + agg[n] @ W2a[128:192,:]
//   out = relu( relu(pre) @ W2b + b2b ).  agg arrives as bf16 (MODE 0) or
//   f32 (fallback) -> template.
// ---------------------------------------------------------------------------
template<int AGGF32>
__global__ __launch_bounds__(256) void node_pass(
    const void* __restrict__ aggp,
    const float* __restrict__ W2a, const float* __restrict__ W2b,
    const float* __restrict__ b2b,
    const float* __restrict__ y2, float* __restrict__ out,
    int N, int ntiles)
{
    const int LDK = 72;
    __shared__ __align__(16) __bf16 wat[64 * 72];   // W2a[128:192,:]^T
    __shared__ __align__(16) __bf16 wbt[64 * 72];   // W2b^T
    __shared__ __align__(16) __bf16 hbuf[4][16 * 72];
    for (int idx = threadIdx.x; idx < 64 * 64; idx += 256) {
        int k = idx >> 6, n = idx & 63;
        wat[n * LDK + k] = (__bf16)W2a[(128 + k) * 64 + n];
        wbt[n * LDK + k] = (__bf16)W2b[k * 64 + n];
    }
    __syncthreads();

    const int lane = threadIdx.x & 63, wave = threadIdx.x >> 6;
    const int l15 = lane & 15, l4 = lane >> 4;
    __bf16* hb = hbuf[wave];

    f32x4 biasb[4];
#pragma unroll
    for (int nt = 0; nt < 4; ++nt) biasb[nt] = *(const f32x4*)(b2b + nt * 16 + l4 * 4);

    for (int tile = blockIdx.x * 4 + wave; tile < ntiles; tile += gridDim.x * 4) {
        const int node = tile * 16 + l15;
        const int nrow = min(node, N - 1);

        f32x4 acc[4];
#pragma unroll
        for (int nt = 0; nt < 4; ++nt)
            acc[nt] = *(const f32x4*)(y2 + (size_t)nrow * 64 + nt * 16 + l4 * 4);
#pragma unroll
        for (int j = 0; j < 2; ++j) {
            const int k0 = j * 32 + l4 * 8;
            bf16x8 b;
            if (AGGF32) b = cvt8((const float*)aggp + (size_t)nrow * 64 + k0);
            else        b = *(const bf16x8*)((const __bf16*)aggp + (size_t)nrow * 64 + k0);
#pragma unroll
            for (int nt = 0; nt < 4; ++nt) {
                bf16x8 a = *(const bf16x8*)(wat + (nt * 16 + l15) * LDK + k0);
                acc[nt] = MFMA(a, b, acc[nt]);
            }
        }
#pragma unroll
        for (int nt = 0; nt < 4; ++nt) {
            bf16x4 hv;
#pragma unroll
            for (int r = 0; r < 4; ++r) hv[r] = (__bf16)fmaxf(acc[nt][r], 0.f);
            *(bf16x4*)(hb + l15 * LDK + nt * 16 + l4 * 4) = hv;
        }

        f32x4 acc2[4];
#pragma unroll
        for (int nt = 0; nt < 4; ++nt) acc2[nt] = biasb[nt];
#pragma unroll
        for (int j = 0; j < 2; ++j) {
            const int k0 = j * 32 + l4 * 8;
            bf16x8 b = *(const bf16x8*)(hb + l15 * LDK + k0);
#pragma unroll
            for (int nt = 0; nt < 4; ++nt) {
                bf16x8 a = *(const bf16x8*)(wbt + (nt * 16 + l15) * LDK + k0);
                acc2[nt] = MFMA(a, b, acc2[nt]);
            }
        }
        if (node < N) {
#pragma unroll
            for (int nt = 0; nt < 4; ++nt) {
                f32x4 v;
#pragma unroll
                for (int r = 0; r < 4; ++r) v[r] = fmaxf(acc2[nt][r], 0.f);
                *(f32x4*)(out + (size_t)node * 64 + nt * 16 + l4 * 4) = v;
            }
        }
    }
}

// ---------------------------------------------------------------------------
extern "C" void kernel_launch(void* const* d_in, const int* in_sizes, int n_in,
                              void* d_out, int out_size, void* d_ws, size_t ws_size,
                              hipStream_t stream) {
    const float* x     = (const float*)d_in[0];
    const int*   eidx  = (const int*)d_in[1];
    const float* eattr = (const float*)d_in[2];
    // d_in[3] = u (unused), d_in[4] = batch (unused)
    const float* W1a = (const float*)d_in[5];
    const float* b1a = (const float*)d_in[6];
    const float* W1b = (const float*)d_in[7];
    const float* b1b = (const float*)d_in[8];
    const float* W2a = (const float*)d_in[9];
    const float* b2a = (const float*)d_in[10];
    const float* W2b = (const float*)d_in[11];
    const float* b2b = (const float*)d_in[12];
    float* out = (float*)d_out;

    const int N = in_sizes[0] / 128;
    const int E = in_sizes[1] / 2;
    const int* send = eidx;
    const int* recv = eidx + E;

    const size_t NG = (size_t)N * 64;
    const size_t need = 2 * NG * sizeof(float) + (size_t)E * 64 * sizeof(__bf16)
                      + (size_t)3 * (N + 1) * sizeof(int);
    const bool big = ws_size >= need;

    const int ntilesN = (N + 15) / 16;
    const int ntilesE = (E + 15) / 16;
    int blkN = (ntilesN + 3) / 4;
    if (blkN > 1024) blkN = 1024;
    int blkE = (ntilesE + 3) / 4;
    if (blkE > 1280) blkE = 1280;
    int blkS = (E + 255) / 256;
    if (blkS > 1024) blkS = 1024;
    int blkR = (N + 3) / 4;
    if (blkR > 2048) blkR = 2048;

    if (big) {
        // layout: y1 | y2 | msgC(bf16) | cnt | offs | cur ; aggB reuses y1
        float*  y1   = (float*)d_ws;
        float*  y2   = y1 + NG;
        __bf16* msgC = (__bf16*)(y2 + NG);
        int*    cnt  = (int*)(msgC + (size_t)E * 64);
        int*    offs = cnt + (N + 1);
        int*    cur  = offs + (N + 1);
        __bf16* aggB = (__bf16*)y1;             // reused after edge_mlp

        zero_i32<<<(N + 256) / 256, 256, 0, stream>>>(cnt, N + 1);
        hist_kernel<<<blkS, 256, 0, stream>>>(recv, cnt, E);
        scan_offsets<<<1, 1024, 0, stream>>>(cnt, offs, cur, N);
        precompute_y<<<blkN, 256, 0, stream>>>(x, W1a, b1a, W2a, b2a, y1, y2, N, ntilesN);
        edge_mlp<0><<<blkE, 256, 0, stream>>>(eattr, send, recv, W1a, W1b, b1b,
                                              y1, cur, msgC, nullptr, E, ntilesE);
        csr_reduce<<<blkR, 256, 0, stream>>>((const unsigned*)msgC, offs, aggB, N);
        node_pass<0><<<blkN, 256, 0, stream>>>(aggB, W2a, W2b, b2b, y2, out, N, ntilesN);
    } else {
        // fallback: agg(f32) | y1 | y2 with device-atomic scatter
        float* agg = (float*)d_ws;
        float* y1  = agg + NG;
        float* y2  = y1 + NG;
        zero_i32<<<2048, 256, 0, stream>>>((int*)agg, (int)NG);
        precompute_y<<<blkN, 256, 0, stream>>>(x, W1a, b1a, W2a, b2a, y1, y2, N, ntilesN);
        edge_mlp<1><<<blkE, 256, 0, stream>>>(eattr, send, recv, W1a, W1b, b1b,
                                              y1, nullptr, nullptr, agg, E, ntilesE);
        node_pass<1><<<blkN, 256, 0, stream>>>(agg, W2a, W2b, b2b, y2, out, N, ntilesN);
    }
}

// Round 8
// 243.918 us; speedup vs baseline: 1.2399x; 1.0226x over previous
//
#include <hip/hip_runtime.h>
#include <hip/hip_bf16.h>

typedef __attribute__((ext_vector_type(8))) __bf16 bf16x8;
typedef __attribute__((ext_vector_type(4))) __bf16 bf16x4;
typedef __attribute__((ext_vector_type(2))) __bf16 bf16x2;
typedef __attribute__((ext_vector_type(4))) float f32x4;

#define MFMA(a, b, c) __builtin_amdgcn_mfma_f32_16x16x32_bf16((a), (b), (c), 0, 0, 0)

__device__ __forceinline__ bf16x8 pack8(f32x4 a, f32x4 b) {
    bf16x8 r;
    r[0] = (__bf16)a[0]; r[1] = (__bf16)a[1]; r[2] = (__bf16)a[2]; r[3] = (__bf16)a[3];
    r[4] = (__bf16)b[0]; r[5] = (__bf16)b[1]; r[6] = (__bf16)b[2]; r[7] = (__bf16)b[3];
    return r;
}

__device__ __forceinline__ bf16x8 cvt8(const float* __restrict__ p) {
    return pack8(*(const f32x4*)(p), *(const f32x4*)(p + 4));
}

// ---------------------------------------------------------------------------
// tiny zero kernel (hipMemsetAsync graph-captures into a 119us fillBuffer)
// ---------------------------------------------------------------------------
__global__ __launch_bounds__(256) void zero_i32(int* __restrict__ p, int n) {
    for (int i = blockIdx.x * blockDim.x + threadIdx.x; i < n;
         i += gridDim.x * blockDim.x)
        p[i] = 0;
}

// ---------------------------------------------------------------------------
// Kernel 1 (transposed): y1 = x @ W1a[0:128,:] + b1a ; y2 = x @ W2a[0:128,:] + b2a
// ---------------------------------------------------------------------------
__global__ __launch_bounds__(256) void precompute_y(
    const float* __restrict__ x,
    const float* __restrict__ W1a, const float* __restrict__ b1a,
    const float* __restrict__ W2a, const float* __restrict__ b2a,
    float* __restrict__ y1, float* __restrict__ y2,
    int N, int ntiles)
{
    const int LDK = 136;                       // 128 + 8 pad
    __shared__ __align__(16) __bf16 w1t[64 * 136];
    __shared__ __align__(16) __bf16 w2t[64 * 136];
    for (int idx = threadIdx.x; idx < 64 * 128; idx += 256) {
        int k = idx >> 6, n = idx & 63;
        w1t[n * LDK + k] = (__bf16)W1a[k * 64 + n];
        w2t[n * LDK + k] = (__bf16)W2a[k * 64 + n];
    }
    __syncthreads();

    const int lane = threadIdx.x & 63, wave = threadIdx.x >> 6;
    const int l15 = lane & 15, l4 = lane >> 4;

    f32x4 bias1[4], bias2[4];
#pragma unroll
    for (int nt = 0; nt < 4; ++nt) {
        bias1[nt] = *(const f32x4*)(b1a + nt * 16 + l4 * 4);
        bias2[nt] = *(const f32x4*)(b2a + nt * 16 + l4 * 4);
    }

    for (int tile = blockIdx.x * 4 + wave; tile < ntiles; tile += gridDim.x * 4) {
        const int node = tile * 16 + l15;
        const int nrow = min(node, N - 1);
        f32x4 acc1[4], acc2[4];
#pragma unroll
        for (int nt = 0; nt < 4; ++nt) {
            acc1[nt] = (f32x4){0.f, 0.f, 0.f, 0.f};
            acc2[nt] = (f32x4){0.f, 0.f, 0.f, 0.f};
        }
#pragma unroll
        for (int j = 0; j < 4; ++j) {
            const int k0 = j * 32 + l4 * 8;
            bf16x8 b = cvt8(x + (size_t)nrow * 128 + k0);     // B = x^T (lane l15 = node)
#pragma unroll
            for (int nt = 0; nt < 4; ++nt) {
                bf16x8 a1 = *(const bf16x8*)(w1t + (nt * 16 + l15) * LDK + k0);  // A = W^T rows
                acc1[nt] = MFMA(a1, b, acc1[nt]);
                bf16x8 a2 = *(const bf16x8*)(w2t + (nt * 16 + l15) * LDK + k0);
                acc2[nt] = MFMA(a2, b, acc2[nt]);
            }
        }
        if (node < N) {
#pragma unroll
            for (int nt = 0; nt < 4; ++nt) {
                f32x4 v1 = acc1[nt] + bias1[nt];
                f32x4 v2 = acc2[nt] + bias2[nt];
                *(f32x4*)(y1 + (size_t)node * 64 + nt * 16 + l4 * 4) = v1;
                *(f32x4*)(y2 + (size_t)node * 64 + nt * 16 + l4 * 4) = v2;
            }
        }
    }
}

// ---------------------------------------------------------------------------
// hist + rank: cnt[rv]++ and rank[e] = arrival order of e within its receiver
// ---------------------------------------------------------------------------
__global__ __launch_bounds__(256) void hist_rank(
    const int* __restrict__ recv, int* __restrict__ cnt,
    int* __restrict__ rank, int E)
{
    for (int e = blockIdx.x * blockDim.x + threadIdx.x; e < E;
         e += gridDim.x * blockDim.x)
        rank[e] = atomicAdd(&cnt[recv[e]], 1);
}

__global__ __launch_bounds__(1024) void scan_offsets(
    const int* __restrict__ cnt, int* __restrict__ offs, int N)
{
    __shared__ int wsum[16];
    __shared__ int stot;
    const int tid = threadIdx.x;
    const int lane = tid & 63, wave = tid >> 6;
    int carry = 0;
    const int CH = 4096;                       // 1024 threads x 4 elems
    for (int base = 0; base < N; base += CH) {
        const int idx = base + tid * 4;
        int v0 = (idx + 0 < N) ? cnt[idx + 0] : 0;
        int v1 = (idx + 1 < N) ? cnt[idx + 1] : 0;
        int v2 = (idx + 2 < N) ? cnt[idx + 2] : 0;
        int v3 = (idx + 3 < N) ? cnt[idx + 3] : 0;
        const int t = v0 + v1 + v2 + v3;
        int s = t;                              // inclusive wave scan
#pragma unroll
        for (int d = 1; d < 64; d <<= 1) {
            int u = __shfl_up(s, d);
            if (lane >= d) s += u;
        }
        if (lane == 63) wsum[wave] = s;
        __syncthreads();
        if (wave == 0) {
            int w = (lane < 16) ? wsum[lane] : 0;
            int ws = w;
#pragma unroll
            for (int d = 1; d < 16; d <<= 1) {
                int u = __shfl_up(ws, d);
                if (lane >= d) ws += u;
            }
            if (lane < 16) wsum[lane] = ws - w;  // exclusive wave offsets
            if (lane == 15) stot = ws;
        }
        __syncthreads();
        const int excl = s - t + wsum[wave] + carry;
        if (idx + 0 < N) offs[idx + 0] = excl;
        if (idx + 1 < N) offs[idx + 1] = excl + v0;
        if (idx + 2 < N) offs[idx + 2] = excl + v0 + v1;
        if (idx + 3 < N) offs[idx + 3] = excl + v0 + v1 + v2;
        carry += stot;
        __syncthreads();                        // protect wsum/stot for next chunk
    }
    if (tid == 0) offs[N] = carry;
}

// ---------------------------------------------------------------------------
// Kernel 2: per-edge MLP. NO atomics: CSR slot p = offs[recv[e]] + rank[e].
// LDS fragment-ordered (bank-rotated by chunk) -> 24.8 KB, 6 blocks/CU.
//   layer1 (transposed): pre1 = y1[send] + eattr @ W1a[128:192,:]
//   layer2 (transposed): msg  = relu(relu(pre1) @ W1b + b1b) -> msgC[p] (bf16)
// MODE 1 fallback: device fp atomics into agg.
// ---------------------------------------------------------------------------
template<int MODE>
__global__ __launch_bounds__(256) void edge_mlp(
    const float* __restrict__ eattr,
    const int* __restrict__ send, const int* __restrict__ recv,
    const int* __restrict__ rank, const int* __restrict__ offs,
    const float* __restrict__ W1a, const float* __restrict__ W1b,
    const float* __restrict__ b1b,
    const float* __restrict__ y1,
    __bf16* __restrict__ msgC, float* agg,
    int E, int ntiles)
{
    // fragment-ordered weights: chunk c = k/8 (k-slice of 8), row n, elem i=k%8
    // addr = (c*65 + n)*8 + i   (65 pad rotates banks per chunk)
    __shared__ __align__(16) __bf16 wfA[8 * 65 * 8];   // W1a[128:192,:]^T
    __shared__ __align__(16) __bf16 wfB[8 * 65 * 8];   // W1b^T
    __shared__ __align__(16) __bf16 hfrag[4][8 * 17 * 8];  // per-wave h fragments
    for (int idx = threadIdx.x; idx < 64 * 64; idx += 256) {
        const int k = idx >> 6, n = idx & 63;
        const int c = k >> 3, i = k & 7;
        wfA[(c * 65 + n) * 8 + i] = (__bf16)W1a[(128 + k) * 64 + n];
        wfB[(c * 65 + n) * 8 + i] = (__bf16)W1b[k * 64 + n];
    }
    __syncthreads();

    const int lane = threadIdx.x & 63, wave = threadIdx.x >> 6;
    const int l15 = lane & 15, l4 = lane >> 4;
    __bf16* hf = hfrag[wave];

    f32x4 biasb[4];
#pragma unroll
    for (int nt = 0; nt < 4; ++nt) biasb[nt] = *(const f32x4*)(b1b + nt * 16 + l4 * 4);

    for (int tile = blockIdx.x * 4 + wave; tile < ntiles; tile += gridDim.x * 4) {
        const int e = tile * 16 + l15;
        const int el = min(e, E - 1);
        const int s = send[el];
        int p = 0, rv = 0;
        if (MODE == 0) {
            rv = recv[el];
            p = offs[rv] + rank[el];           // CSR slot, no atomic
        } else {
            rv = recv[el];
        }

        // ---- layer 1 (transposed): C-init = y1[send] vectorized gather
        f32x4 acc[4];
#pragma unroll
        for (int nt = 0; nt < 4; ++nt)
            acc[nt] = *(const f32x4*)(y1 + (size_t)s * 64 + nt * 16 + l4 * 4);
#pragma unroll
        for (int j = 0; j < 2; ++j) {
            const float* ep = eattr + (size_t)el * 64 + j * 32 + l4 * 8;
            bf16x8 b = pack8(*(const f32x4*)ep, *(const f32x4*)(ep + 4));
            const int c = j * 4 + l4;
#pragma unroll
            for (int nt = 0; nt < 4; ++nt) {
                bf16x8 a = *(const bf16x8*)(wfA + ((c * 65) + nt * 16 + l15) * 8);
                acc[nt] = MFMA(a, b, acc[nt]);
            }
        }
        // ---- relu -> stage h in fragment order (chunk c2 = col/8)
#pragma unroll
        for (int nt = 0; nt < 4; ++nt) {
            bf16x4 hv;
#pragma unroll
            for (int r = 0; r < 4; ++r) hv[r] = (__bf16)fmaxf(acc[nt][r], 0.f);
            const int c2 = nt * 2 + (l4 >> 1);
            *(bf16x4*)(hf + (c2 * 17 + l15) * 8 + (l4 & 1) * 4) = hv;
        }
        // ---- layer 2 (transposed): lane l15 = edge, cols nt*16 + l4*4 + r
        f32x4 acc2[4];
#pragma unroll
        for (int nt = 0; nt < 4; ++nt) acc2[nt] = biasb[nt];
#pragma unroll
        for (int j = 0; j < 2; ++j) {
            const int c = j * 4 + l4;
            bf16x8 b = *(const bf16x8*)(hf + (c * 17 + l15) * 8);
#pragma unroll
            for (int nt = 0; nt < 4; ++nt) {
                bf16x8 a = *(const bf16x8*)(wfB + ((c * 65) + nt * 16 + l15) * 8);
                acc2[nt] = MFMA(a, b, acc2[nt]);
            }
        }
        // ---- emit
        if (e < E) {
            if (MODE == 0) {
                __bf16* row = msgC + (size_t)p * 64;
#pragma unroll
                for (int nt = 0; nt < 4; ++nt) {
                    bf16x4 mv;
#pragma unroll
                    for (int r = 0; r < 4; ++r) mv[r] = (__bf16)fmaxf(acc2[nt][r], 0.f);
                    *(bf16x4*)(row + nt * 16 + l4 * 4) = mv;
                }
            } else {
                float* base = agg + (size_t)rv * 64 + l4 * 4;
#pragma unroll
                for (int nt = 0; nt < 4; ++nt)
#pragma unroll
                    for (int r = 0; r < 4; ++r)
                        unsafeAtomicAdd(base + nt * 16 + r, fmaxf(acc2[nt][r], 0.f));
            }
        }
    }
}

// ---------------------------------------------------------------------------
// CSR reduce (streaming): msg rows for node n are CONTIGUOUS [offs[n],offs[n+1]).
// One wave per node; halves take alternate rows; lane sums 2 columns in f32.
// ---------------------------------------------------------------------------
__global__ __launch_bounds__(256) void csr_reduce(
    const unsigned* __restrict__ msg_u,
    const int* __restrict__ offs,
    __bf16* __restrict__ aggB, int N)
{
    const int wave = threadIdx.x >> 6, lane = threadIdx.x & 63;
    const int half = lane >> 5, c = lane & 31;
    for (int node = blockIdx.x * 4 + wave; node < N; node += gridDim.x * 4) {
        const int oL = offs[node], oR = offs[node + 1];
        float ax = 0.f, ay = 0.f;
        for (int p = oL + half; p < oR; p += 2) {
            const unsigned u = msg_u[(size_t)p * 32 + c];
            ax += __uint_as_float(u << 16);
            ay += __uint_as_float(u & 0xffff0000u);
        }
        ax += __shfl_xor(ax, 32);
        ay += __shfl_xor(ay, 32);
        if (half == 0) {
            bf16x2 v; v[0] = (__bf16)ax; v[1] = (__bf16)ay;
            *(bf16x2*)(aggB + (size_t)node * 64 + c * 2) = v;
        }
    }
}

// ---------------------------------------------------------------------------
// Kernel 3 (transposed): per-node  pre = y2[n] + agg[n] @ W2a[128:192,:]
//   out = relu( relu(pre) @ W2b + b2b )
// ---------------------------------------------------------------------------
template<int AGGF32>
__global__ __launch_bounds__(256) void node_pass(
    const void* __restrict__ aggp,
    const float* __restrict__ W2a, const float* __restrict__ W2b,
    const float* __restrict__ b2b,
    const float* __restrict__ y2, float* __restrict__ out,
    int N, int ntiles)
{
    const int LDK = 72;
    __shared__ __align__(16) __bf16 wat[64 * 72];   // W2a[128:192,:]^T
    __shared__ __align__(16) __bf16 wbt[64 * 72];   // W2b^T
    __shared__ __align__(16) __bf16 hbuf[4][16 * 72];
    for (int idx = threadIdx.x; idx < 64 * 64; idx += 256) {
        int k = idx >> 6, n = idx & 63;
        wat[n * LDK + k] = (__bf16)W2a[(128 + k) * 64 + n];
        wbt[n * LDK + k] = (__bf16)W2b[k * 64 + n];
    }
    __syncthreads();

    const int lane = threadIdx.x & 63, wave = threadIdx.x >> 6;
    const int l15 = lane & 15, l4 = lane >> 4;
    __bf16* hb = hbuf[wave];

    f32x4 biasb[4];
#pragma unroll
    for (int nt = 0; nt < 4; ++nt) biasb[nt] = *(const f32x4*)(b2b + nt * 16 + l4 * 4);

    for (int tile = blockIdx.x * 4 + wave; tile < ntiles; tile += gridDim.x * 4) {
        const int node = tile * 16 + l15;
        const int nrow = min(node, N - 1);

        f32x4 acc[4];
#pragma unroll
        for (int nt = 0; nt < 4; ++nt)
            acc[nt] = *(const f32x4*)(y2 + (size_t)nrow * 64 + nt * 16 + l4 * 4);
#pragma unroll
        for (int j = 0; j < 2; ++j) {
            const int k0 = j * 32 + l4 * 8;
            bf16x8 b;
            if (AGGF32) b = cvt8((const float*)aggp + (size_t)nrow * 64 + k0);
            else        b = *(const bf16x8*)((const __bf16*)aggp + (size_t)nrow * 64 + k0);
#pragma unroll
            for (int nt = 0; nt < 4; ++nt) {
                bf16x8 a = *(const bf16x8*)(wat + (nt * 16 + l15) * LDK + k0);
                acc[nt] = MFMA(a, b, acc[nt]);
            }
        }
#pragma unroll
        for (int nt = 0; nt < 4; ++nt) {
            bf16x4 hv;
#pragma unroll
            for (int r = 0; r < 4; ++r) hv[r] = (__bf16)fmaxf(acc[nt][r], 0.f);
            *(bf16x4*)(hb + l15 * LDK + nt * 16 + l4 * 4) = hv;
        }

        f32x4 acc2[4];
#pragma unroll
        for (int nt = 0; nt < 4; ++nt) acc2[nt] = biasb[nt];
#pragma unroll
        for (int j = 0; j < 2; ++j) {
            const int k0 = j * 32 + l4 * 8;
            bf16x8 b = *(const bf16x8*)(hb + l15 * LDK + k0);
#pragma unroll
            for (int nt = 0; nt < 4; ++nt) {
                bf16x8 a = *(const bf16x8*)(wbt + (nt * 16 + l15) * LDK + k0);
                acc2[nt] = MFMA(a, b, acc2[nt]);
            }
        }
        if (node < N) {
#pragma unroll
            for (int nt = 0; nt < 4; ++nt) {
                f32x4 v;
#pragma unroll
                for (int r = 0; r < 4; ++r) v[r] = fmaxf(acc2[nt][r], 0.f);
                *(f32x4*)(out + (size_t)node * 64 + nt * 16 + l4 * 4) = v;
            }
        }
    }
}

// ---------------------------------------------------------------------------
extern "C" void kernel_launch(void* const* d_in, const int* in_sizes, int n_in,
                              void* d_out, int out_size, void* d_ws, size_t ws_size,
                              hipStream_t stream) {
    const float* x     = (const float*)d_in[0];
    const int*   eidx  = (const int*)d_in[1];
    const float* eattr = (const float*)d_in[2];
    // d_in[3] = u (unused), d_in[4] = batch (unused)
    const float* W1a = (const float*)d_in[5];
    const float* b1a = (const float*)d_in[6];
    const float* W1b = (const float*)d_in[7];
    const float* b1b = (const float*)d_in[8];
    const float* W2a = (const float*)d_in[9];
    const float* b2a = (const float*)d_in[10];
    const float* W2b = (const float*)d_in[11];
    const float* b2b = (const float*)d_in[12];
    float* out = (float*)d_out;

    const int N = in_sizes[0] / 128;
    const int E = in_sizes[1] / 2;
    const int* send = eidx;
    const int* recv = eidx + E;

    const size_t NG = (size_t)N * 64;
    const size_t need = 2 * NG * sizeof(float) + (size_t)E * 64 * sizeof(__bf16)
                      + ((size_t)2 * (N + 1) + E) * sizeof(int);
    const bool big = ws_size >= need;

    const int ntilesN = (N + 15) / 16;
    const int ntilesE = (E + 15) / 16;
    int blkN = (ntilesN + 3) / 4;
    if (blkN > 1024) blkN = 1024;
    int blkE = (ntilesE + 3) / 4;
    if (blkE > 1536) blkE = 1536;   // 6 blocks/CU (24.8 KB LDS)
    int blkS = (E + 255) / 256;
    if (blkS > 1024) blkS = 1024;
    int blkR = (N + 3) / 4;
    if (blkR > 2048) blkR = 2048;

    if (big) {
        // layout: y1 | y2 | msgC(bf16) | cnt | offs | rank ; aggB reuses y1
        float*  y1   = (float*)d_ws;
        float*  y2   = y1 + NG;
        __bf16* msgC = (__bf16*)(y2 + NG);
        int*    cnt  = (int*)(msgC + (size_t)E * 64);
        int*    offs = cnt + (N + 1);
        int*    rank = offs + (N + 1);
        __bf16* aggB = (__bf16*)y1;             // reused after edge_mlp

        zero_i32<<<(N + 256) / 256, 256, 0, stream>>>(cnt, N + 1);
        hist_rank<<<blkS, 256, 0, stream>>>(recv, cnt, rank, E);
        scan_offsets<<<1, 1024, 0, stream>>>(cnt, offs, N);
        precompute_y<<<blkN, 256, 0, stream>>>(x, W1a, b1a, W2a, b2a, y1, y2, N, ntilesN);
        edge_mlp<0><<<blkE, 256, 0, stream>>>(eattr, send, recv, rank, offs,
                                              W1a, W1b, b1b, y1, msgC, nullptr, E, ntilesE);
        csr_reduce<<<blkR, 256, 0, stream>>>((const unsigned*)msgC, offs, aggB, N);
        node_pass<0><<<blkN, 256, 0, stream>>>(aggB, W2a, W2b, b2b, y2, out, N, ntilesN);
    } else {
        // fallback: agg(f32) | y1 | y2 with device-atomic scatter
        float* agg = (float*)d_ws;
        float* y1  = agg + NG;
        float* y2  = y1 + NG;
        zero_i32<<<2048, 256, 0, stream>>>((int*)agg, (int)NG);
        precompute_y<<<blkN, 256, 0, stream>>>(x, W1a, b1a, W2a, b2a, y1, y2, N, ntilesN);
        edge_mlp<1><<<blkE, 256, 0, stream>>>(eattr, send, recv, nullptr, nullptr,
                                              W1a, W1b, b1b, y1, nullptr, agg, E, ntilesE);
        node_pass<1><<<blkN, 256, 0, stream>>>(agg, W2a, W2b, b2b, y2, out, N, ntilesN);
    }
}